// Round 6
// baseline (445.665 us; speedup 1.0000x reference)
//
#include <hip/hip_runtime.h>
#include <stdint.h>

#define NROWS 65536
#define DCOL  480      // 128 + 3*64 + 5*32
#define RT    16       // rows per block

#define INV_S0 0.08838834764831845f   // 1/sqrt(128)
#define INV_S1 0.125f                  // 1/8
#define INV_S2 0.17677669529663687f    // 1/sqrt(32)
#define INV_T0 0.044194173824159216f   // 1/sqrt(512)
#define INV_T1 0.0625f                 // 1/16
#define INV_T2 0.08838834764831845f    // 1/sqrt(128)

// d_ws element offsets (uint16_t units), fragment-linear transposed layouts Wt[n][k]
#define OFF_W0T 0         // [896][128]  (x INV_S0 folded)
#define OFF_W1T 114688    // [256][64]   (x INV_S1)
#define OFF_W2T 131072    // [128][32]   (x INV_S2)
#define OFF_V0T 135168    // [128][512]  (x INV_T0)
#define OFF_V1T 200704    // [64][256]   (x INV_T1)
#define OFF_V2T 217088    // [32][128]   (x INV_T2)
#define TOT_W   221184

typedef __attribute__((ext_vector_type(8))) short  short8;
typedef __attribute__((ext_vector_type(4))) float  floatx4;

__device__ __forceinline__ uint16_t f2bf(float x){
  uint32_t u = __builtin_bit_cast(uint32_t, x);
  return (uint16_t)((u + 0x8000u) >> 16);
}
__device__ __forceinline__ float bf2f(uint16_t h){
  return __builtin_bit_cast(float, (uint32_t)h << 16);
}

#define MFMA16(a,b,c) __builtin_amdgcn_mfma_f32_16x16x32_bf16((a),(b),(c),0,0,0)

// ---------------- weight conversion pre-pass: fp32 row-major -> bf16 Wt[n][k], scale folded
__global__ __launch_bounds__(256)
void convert_weights(const float* __restrict__ W0, const float* __restrict__ W1,
                     const float* __restrict__ W2, const float* __restrict__ V0,
                     const float* __restrict__ V1, const float* __restrict__ V2,
                     uint16_t* __restrict__ wt)
{
  const int tid = blockIdx.x*256 + threadIdx.x;
  if (tid >= TOT_W) return;
  if (tid < OFF_W1T){
    const int i = tid;            const int n = i>>7, k = i&127;
    wt[tid] = f2bf(W0[(size_t)k*896 + n] * INV_S0);
  } else if (tid < OFF_W2T){
    const int i = tid - OFF_W1T;  const int n = i>>6, k = i&63;
    wt[tid] = f2bf(W1[(size_t)k*256 + n] * INV_S1);
  } else if (tid < OFF_V0T){
    const int i = tid - OFF_W2T;  const int n = i>>5, k = i&31;
    wt[tid] = f2bf(W2[(size_t)k*128 + n] * INV_S2);
  } else if (tid < OFF_V1T){
    const int i = tid - OFF_V0T;  const int n = i>>9, k = i&511;
    wt[tid] = f2bf(V0[(size_t)k*128 + n] * INV_T0);
  } else if (tid < OFF_V2T){
    const int i = tid - OFF_V1T;  const int n = i>>8, k = i&255;
    wt[tid] = f2bf(V1[(size_t)k*64 + n] * INV_T1);
  } else {
    const int i = tid - OFF_V2T;  const int n = i>>7, k = i&127;
    wt[tid] = f2bf(V2[(size_t)k*32 + n] * INV_T2);
  }
}

// ---------------- fused main kernel: 16 rows / 12 waves (768 thr) / 4 barriers
// R6 change vs R5: same schedule+LDS, work spread over 12 waves instead of 8 ->
// 24 waves/CU (6/SIMD, 1.5x) for latency hiding; role-split removes the o0->h2
// serial chain inside W1. launch_bounds pins VGPR<=85 so 6 waves/EU holds.
// Schedule: P1(norms) | P2(h0 -> s,g) | W1(o0: w0-7 ∥ h2 all-m: w8-11 -> z2x5) |
//           W2(h1 all-m -> z1x3: w0-9 ∥ o2 all-m: w10-11) | W3(o1: 1 task/wave)
// LDS pool 68608 B (lifetime-overlapped), 2 blocks/CU x 12 waves = 24 waves/CU.
__global__ __launch_bounds__(768, 6)
void ffn_mfma(const float* __restrict__ x,  const float* __restrict__ nw0,
              const float* __restrict__ nb0,const float* __restrict__ nw1,
              const float* __restrict__ nw2,const float* __restrict__ b0,
              const float* __restrict__ c0, const float* __restrict__ alpha,
              const uint16_t* __restrict__ wt, float* __restrict__ out)
{
  __shared__ __align__(16) uint16_t pool[34304];   // 68608 B

  uint16_t (*gbf )[392]      = (uint16_t (*)[392])     (pool);           // [16][392]
  uint16_t (*y1bf)[16][72]   = (uint16_t (*)[16][72])  (pool + 6272);    // [3][16][72]
  uint16_t (*z2bf)[16][136]  = (uint16_t (*)[16][136]) (pool + 9728);    // [5][16][136]
  uint16_t (*z1bf)[16][264]  = (uint16_t (*)[16][264]) (pool + 20608);   // [3][16][264]
  uint16_t (*y2bf)[16][40]   = (uint16_t (*)[16][40])  (pool + 20608);   // [5][16][40]
  uint16_t (*sbf )[520]      = (uint16_t (*)[520])     (pool + 23808);   // [16][520]
  uint16_t (*y0bf)[136]      = (uint16_t (*)[136])     (pool + 32128);   // [16][136]

  const int t      = threadIdx.x;
  const int wave   = t >> 6, lane = t & 63;
  const int lane16 = lane & 15, quad = lane >> 4;
  const int row0   = blockIdx.x * RT;
  const float ta   = tanhf(alpha[0]);
  const floatx4 fz = {0.f,0.f,0.f,0.f};

  // ---------- P1: norms -> y0/y1/y2 (waves 0-3: rows {w,w+12}; waves 4-11: row w) ----------
  {
    const int nr = (wave < 4) ? 2 : 1;
    float wA[8], wB[8]; int uu[8], mmv[8];
    #pragma unroll
    for (int i=0;i<8;++i){
      const int e = lane + i*64;
      if (e < 128){ uu[i]=e; mmv[i]=0; wA[i]=nw0[e]; wB[i]=nb0[e]; }
      else if (e < 320){ const int d=e-128; const int u=d/3; uu[i]=u; mmv[i]=d-3*u; wA[i]=nw1[u]; wB[i]=0.f; }
      else if (e < DCOL){ const int d=e-320; const int u=d/5; uu[i]=u; mmv[i]=d-5*u; wA[i]=nw2[u]; wB[i]=0.f; }
      else { uu[i]=0; mmv[i]=0; wA[i]=0.f; wB[i]=0.f; }
    }
    #pragma unroll
    for (int rr=0; rr<2; ++rr){
      if (rr >= nr) break;
      const int r = (rr == 0) ? wave : wave + 12;
      const float* xr = x + (size_t)(row0 + r)*DCOL;
      float xv[8];
      #pragma unroll
      for (int i=0;i<8;++i){ const int e = lane + i*64; xv[i] = (e < DCOL) ? xr[e] : 0.f; }
      float s0  = xv[0] + xv[1];
      float s0q = xv[0]*xv[0] + xv[1]*xv[1];
      float q1  = xv[2]*xv[2] + xv[3]*xv[3] + xv[4]*xv[4];
      float q2  = xv[5]*xv[5] + xv[6]*xv[6] + xv[7]*xv[7];
      #pragma unroll
      for (int off=32; off>0; off>>=1){
        s0  += __shfl_xor(s0,  off);
        s0q += __shfl_xor(s0q, off);
        q1  += __shfl_xor(q1,  off);
        q2  += __shfl_xor(q2,  off);
      }
      const float mu   = s0 * (1.f/128.f);
      const float var  = s0q * (1.f/128.f) - mu*mu;
      const float rstd = rsqrtf(var + 1e-8f);
      const float inv  = rsqrtf(0.5f*(q1*(1.f/192.f) + q2*(1.f/160.f)) + 1e-8f);
      #pragma unroll
      for (int i=0;i<8;++i){
        const int e = lane + i*64;
        if (e < 128)       y0bf[r][e] = f2bf((xv[i]-mu)*rstd*wA[i] + wB[i]);
        else if (e < 320)  y1bf[mmv[i]][r][uu[i]] = f2bf(xv[i]*inv*wA[i]);
        else if (e < DCOL) y2bf[mmv[i]][r][uu[i]] = f2bf(xv[i]*inv*wA[i]);
      }
    }
  }
  __syncthreads();

  // ---------- P2: h0 = y0@W0 + b0 -> silu/sigmoid -> sbf/gbf (waves 0-7: 5 tiles, 8-11: 4) ----------
  {
    short8 a0[4];
    #pragma unroll
    for (int kk=0; kk<4; ++kk)
      a0[kk] = *(const short8*)&y0bf[lane16][kk*32 + quad*8];
    const uint16_t* W0t = wt + OFF_W0T;
    const int base = (wave < 8) ? wave*5 : 40 + (wave-8)*4;
    const int nt   = (wave < 8) ? 5 : 4;
    #pragma unroll 1
    for (int it=0; it<nt; ++it){
      const int tile = base + it;
      floatx4 acc = fz;
      #pragma unroll
      for (int kk=0;kk<4;++kk){
        const short8 b = *(const short8*)(W0t + (size_t)(tile*16+lane16)*128 + kk*32 + quad*8);
        acc = MFMA16(a0[kk], b, acc);
      }
      const int col  = tile*16 + lane16;
      const float bias = b0[col];
      #pragma unroll
      for (int r2=0; r2<4; ++r2){
        const int row = quad*4 + r2;
        const float h  = acc[r2] + bias;
        const float sg = 1.f/(1.f + __expf(-h));
        if (col < 512) sbf[row][col]       = f2bf(h*sg);   // silu
        else           gbf[row][col - 512] = f2bf(sg);     // gate
      }
    }
  }
  __syncthreads();

  // ---------- W1: o0 = s@V0 + c0 (waves 0-7, tile=wave) ∥ h2 ALL m -> z2x5 (waves 8-11, 2 tiles) ----------
  {
    if (wave < 8){
      const uint16_t* V0t = wt + OFF_V0T;
      const int col = wave*16 + lane16;           // [0,128)
      float xra[4];
      #pragma unroll
      for (int r2=0;r2<4;++r2)
        xra[r2] = x[(size_t)(row0+quad*4+r2)*DCOL + col];
      const float cc = c0[col];
      floatx4 acc = fz;
      #pragma unroll 4
      for (int kk=0; kk<16; ++kk){
        const short8 a = *(const short8*)&sbf[lane16][kk*32 + quad*8];
        const short8 b = *(const short8*)(V0t + (size_t)col*512 + kk*32 + quad*8);
        acc = MFMA16(a, b, acc);
      }
      #pragma unroll
      for (int r2=0;r2<4;++r2)
        out[(size_t)(row0+quad*4+r2)*DCOL + col] = xra[r2] + ta*(acc[r2]+cc);
    } else {
      const uint16_t* W2t = wt + OFF_W2T;
      short8 a2[5];
      #pragma unroll
      for (int m=0;m<5;++m) a2[m] = *(const short8*)&y2bf[m][lane16][quad*8];
      #pragma unroll
      for (int tt=0; tt<2; ++tt){
        const int col = (2*(wave-8)+tt)*16 + lane16;    // [0,128)
        const short8 b2 = *(const short8*)(W2t + (size_t)col*32 + quad*8);
        float g2v[4];
        #pragma unroll
        for (int r2=0;r2<4;++r2) g2v[r2] = bf2f(gbf[quad*4+r2][256+col]);
        #pragma unroll
        for (int m=0;m<5;++m){
          floatx4 h = MFMA16(a2[m], b2, fz);
          #pragma unroll
          for (int r2=0;r2<4;++r2)
            z2bf[m][quad*4+r2][col] = f2bf(h[r2]*g2v[r2]);
        }
      }
    }
  }
  __syncthreads();

  // ---------- W2: h1 ALL m -> z1x3 (waves 0-9) ∥ o2 ALL m (waves 10,11, reads z2) ----------
  {
    if (wave < 10){
      const uint16_t* W1t = wt + OFF_W1T;
      short8 a1[3][2];
      #pragma unroll
      for (int m=0;m<3;++m){
        a1[m][0] = *(const short8*)&y1bf[m][lane16][quad*8];
        a1[m][1] = *(const short8*)&y1bf[m][lane16][32 + quad*8];
      }
      const int nt    = (wave < 6) ? 2 : 1;
      const int tbase = (wave < 6) ? 2*wave : 12 + (wave-6);
      #pragma unroll
      for (int tt=0; tt<2; ++tt){
        if (tt >= nt) break;
        const int col = (tbase+tt)*16 + lane16;      // [0,256)
        const short8 b0f = *(const short8*)(W1t + (size_t)col*64 + quad*8);
        const short8 b1f = *(const short8*)(W1t + (size_t)col*64 + 32 + quad*8);
        float gv[4];
        #pragma unroll
        for (int r2=0;r2<4;++r2) gv[r2] = bf2f(gbf[quad*4+r2][col]);
        #pragma unroll
        for (int m=0;m<3;++m){
          floatx4 am = MFMA16(a1[m][0], b0f, fz);
          am = MFMA16(a1[m][1], b1f, am);
          #pragma unroll
          for (int r2=0;r2<4;++r2)
            z1bf[m][quad*4+r2][col] = f2bf(am[r2]*gv[r2]);
        }
      }
    } else {
      const uint16_t* V2t = wt + OFF_V2T;
      const int col = (wave-10)*16 + lane16;         // [0,32)
      short8 ob[4];
      #pragma unroll
      for (int kk=0;kk<4;++kk)
        ob[kk] = *(const short8*)(V2t + (size_t)col*128 + kk*32 + quad*8);
      float xo[5][4];
      #pragma unroll
      for (int m=0;m<5;++m)
        #pragma unroll
        for (int r2=0;r2<4;++r2)
          xo[m][r2] = x[(size_t)(row0+quad*4+r2)*DCOL + 320 + col*5 + m];
      floatx4 am[5];
      #pragma unroll
      for (int m=0;m<5;++m){
        am[m] = fz;
        #pragma unroll
        for (int kk=0;kk<4;++kk){
          const short8 a = *(const short8*)&z2bf[m][lane16][kk*32 + quad*8];
          am[m] = MFMA16(a, ob[kk], am[m]);
        }
      }
      #pragma unroll
      for (int m=0;m<5;++m)
        #pragma unroll
        for (int r2=0;r2<4;++r2){
          const size_t idx = (size_t)(row0+quad*4+r2)*DCOL + 320 + col*5 + m;
          out[idx] = xo[m][r2] + ta*am[m][r2];
        }
    }
  }
  __syncthreads();

  // ---------- W3: o1 (reads z1) — exactly one (m, col-tile) task per wave ----------
  {
    const uint16_t* V1t = wt + OFF_V1T;
    const int m   = wave >> 2;                       // 0,1,2
    const int col = (wave & 3)*16 + lane16;          // [0,64)
    short8 vb[8];
    #pragma unroll
    for (int kk=0;kk<8;++kk)
      vb[kk] = *(const short8*)(V1t + (size_t)col*256 + kk*32 + quad*8);
    float xr[4];
    #pragma unroll
    for (int r2=0;r2<4;++r2)
      xr[r2] = x[(size_t)(row0+quad*4+r2)*DCOL + 128 + col*3 + m];
    floatx4 am = fz;
    #pragma unroll
    for (int kk=0;kk<8;++kk){
      const short8 f = *(const short8*)&z1bf[m][lane16][kk*32 + quad*8];
      am = MFMA16(f, vb[kk], am);
    }
    #pragma unroll
    for (int r2=0;r2<4;++r2)
      out[(size_t)(row0+quad*4+r2)*DCOL + 128 + col*3 + m] = xr[r2] + ta*am[r2];
  }
}

extern "C" void kernel_launch(void* const* d_in, const int* in_sizes, int n_in,
                              void* d_out, int out_size, void* d_ws, size_t ws_size,
                              hipStream_t stream) {
  const float* x   = (const float*)d_in[0];
  const float* nw0 = (const float*)d_in[1];
  const float* nb0 = (const float*)d_in[2];
  const float* nw1 = (const float*)d_in[3];
  const float* nw2 = (const float*)d_in[4];
  const float* W0  = (const float*)d_in[5];
  const float* b0  = (const float*)d_in[6];
  const float* W1  = (const float*)d_in[7];
  const float* W2  = (const float*)d_in[8];
  const float* V0  = (const float*)d_in[9];
  const float* c0  = (const float*)d_in[10];
  const float* V1  = (const float*)d_in[11];
  const float* V2  = (const float*)d_in[12];
  const float* al  = (const float*)d_in[13];
  uint16_t* wt = (uint16_t*)d_ws;   // needs 442368 B

  convert_weights<<<dim3((TOT_W + 255)/256), dim3(256), 0, stream>>>(
      W0, W1, W2, V0, V1, V2, wt);
  ffn_mfma<<<dim3(NROWS/RT), dim3(768), 0, stream>>>(
      x, nw0, nb0, nw1, nw2, b0, c0, al, wt, (float*)d_out);
}